// Round 10
// baseline (401.780 us; speedup 1.0000x reference)
//
#include <hip/hip_runtime.h>
#include <hip/hip_bf16.h>
#include <math.h>

#define N_NUC_C 100000
#define N_NN_C  1600000
#define EMB_C   128
#define MSG_C   32
#define OUT_C   128
#define NB1     98   // ceil(N_NUC / 1024) for the scan
#define NPART   8
#define R_PER_P (N_NUC_C / NPART)          // 12500 receivers per partition
#define SBLK    784                        // blocks per partition in scatter
#define STHREADS (SBLK * 256)              // 200704 threads per partition
#define EV_STR  20                         // uints per e-row (16 data + 4 pad, 80 B aligned)
#define PS_STR  36                         // floats per proj_s row (32 data + 4 pad, 144 B aligned)

__device__ __forceinline__ float silu_f(float y) {
    return y / (1.0f + __expf(-y));
}

// round-to-nearest-even f32->bf16, packed pair (a -> low 16, b -> high 16)
__device__ __forceinline__ unsigned pack_bf16x2(float a, float b) {
    unsigned ua = __float_as_uint(a); ua += 0x7FFFu + ((ua >> 16) & 1u);
    unsigned ub = __float_as_uint(b); ub += 0x7FFFu + ((ub >> 16) & 1u);
    return (ua >> 16) | (ub & 0xFFFF0000u);
}

// ---------------------------------------------------------------------------
// Kernel A: node projections  proj[pr][n][c] = embed[n] @ W + b
// ---------------------------------------------------------------------------
__global__ __launch_bounds__(256) void proj_kernel(
    const float* __restrict__ s_embed, const float* __restrict__ r_embed,
    const float* __restrict__ W_s, const float* __restrict__ b_s,
    const float* __restrict__ W_r, const float* __restrict__ b_r,
    float* __restrict__ proj /* [2][N_NUC][MSG] */)
{
    const int n   = blockIdx.x * blockDim.x + threadIdx.x;
    const int sub = blockIdx.y;       // 0..3
    const int pr  = sub >> 1;
    const int c0  = (sub & 1) * 16;
    if (n >= N_NUC_C) return;

    const float* __restrict__ src = pr ? r_embed : s_embed;
    const float* __restrict__ W   = pr ? W_r : W_s;
    const float* __restrict__ b   = pr ? b_r : b_s;
    float* __restrict__ dst = proj + (size_t)pr * N_NUC_C * MSG_C;

    float acc[16];
    #pragma unroll
    for (int i = 0; i < 16; ++i) acc[i] = b[c0 + i];

    const float* row = src + (size_t)n * EMB_C;
    #pragma unroll 4
    for (int k = 0; k < EMB_C; k += 4) {
        const float4 rv = *reinterpret_cast<const float4*>(row + k);
        #pragma unroll
        for (int i = 0; i < 16; ++i) {
            acc[i] = fmaf(rv.x, W[(k + 0) * MSG_C + c0 + i], acc[i]);
            acc[i] = fmaf(rv.y, W[(k + 1) * MSG_C + c0 + i], acc[i]);
            acc[i] = fmaf(rv.z, W[(k + 2) * MSG_C + c0 + i], acc[i]);
            acc[i] = fmaf(rv.w, W[(k + 3) * MSG_C + c0 + i], acc[i]);
        }
    }

    float4* d = reinterpret_cast<float4*>(dst + (size_t)n * MSG_C + c0);
    d[0] = make_float4(acc[0],  acc[1],  acc[2],  acc[3]);
    d[1] = make_float4(acc[4],  acc[5],  acc[6],  acc[7]);
    d[2] = make_float4(acc[8],  acc[9],  acc[10], acc[11]);
    d[3] = make_float4(acc[12], acc[13], acc[14], acc[15]);
}

// ---------------------------------------------------------------------------
// CSR build: single atomic pass — rank[e] = running index within receiver
// ---------------------------------------------------------------------------
__global__ __launch_bounds__(256) void rank_kernel(
    const int* __restrict__ receivers, int* __restrict__ cnt,
    int* __restrict__ rank)
{
    const int e = blockIdx.x * blockDim.x + threadIdx.x;
    if (e >= N_NN_C) return;
    rank[e] = atomicAdd(&cnt[receivers[e]], 1);
}

// Exclusive scan of cnt[N_NUC] -> offsets. Three tiny kernels.
__global__ __launch_bounds__(256) void scan1_kernel(
    const int* __restrict__ cnt, int* __restrict__ excl, int* __restrict__ blockTot)
{
    __shared__ int waveTot[4];
    const int t = threadIdx.x, b = blockIdx.x;
    const int lane = t & 63, wid = t >> 6;
    const int base = b * 1024 + t * 4;

    int d0 = (base + 0 < N_NUC_C) ? cnt[base + 0] : 0;
    int d1 = (base + 1 < N_NUC_C) ? cnt[base + 1] : 0;
    int d2 = (base + 2 < N_NUC_C) ? cnt[base + 2] : 0;
    int d3 = (base + 3 < N_NUC_C) ? cnt[base + 3] : 0;
    const int s = d0 + d1 + d2 + d3;

    int incl = s;
    #pragma unroll
    for (int off = 1; off < 64; off <<= 1) {
        int v = __shfl_up(incl, off);
        if (lane >= off) incl += v;
    }
    const int wexcl = incl - s;
    if (lane == 63) waveTot[wid] = incl;
    __syncthreads();
    int wbase = 0;
    for (int w = 0; w < wid; ++w) wbase += waveTot[w];
    const int e0 = wbase + wexcl;

    if (base + 0 < N_NUC_C) excl[base + 0] = e0;
    if (base + 1 < N_NUC_C) excl[base + 1] = e0 + d0;
    if (base + 2 < N_NUC_C) excl[base + 2] = e0 + d0 + d1;
    if (base + 3 < N_NUC_C) excl[base + 3] = e0 + d0 + d1 + d2;
    if (t == 255) blockTot[b] = wbase + incl;
}

__global__ __launch_bounds__(128) void scan2_kernel(
    const int* __restrict__ blockTot, int* __restrict__ blockOff)
{
    __shared__ int sh[128];
    const int t = threadIdx.x;
    const int v = (t < NB1) ? blockTot[t] : 0;
    sh[t] = v;
    __syncthreads();
    #pragma unroll
    for (int off = 1; off < 128; off <<= 1) {
        int x = 0;
        if (t >= off) x = sh[t - off];
        __syncthreads();
        sh[t] += x;
        __syncthreads();
    }
    if (t < NB1) blockOff[t] = sh[t] - v;
}

__global__ __launch_bounds__(256) void scan3_kernel(
    const int* __restrict__ excl, const int* __restrict__ blockOff,
    int* __restrict__ offsets)
{
    const int n = blockIdx.x * blockDim.x + threadIdx.x;
    if (n < N_NUC_C) offsets[n] = excl[n] + blockOff[n >> 10];
    if (n == 0) offsets[N_NUC_C] = N_NN_C;
}

// ---------------------------------------------------------------------------
// Partition-local ATOMIC-FREE scatter: 8 receiver ranges; blocks with
// blockIdx%8==p scan all edges (coalesced) and write int4 (e,s,r,0) to
// dst = offsets[r] + rank[e]. Partition-clustered -> L2 write coalescing.
// ---------------------------------------------------------------------------
__global__ __launch_bounds__(256) void scatter_pack8_kernel(
    const int* __restrict__ senders, const int* __restrict__ receivers,
    const int* __restrict__ rank, const int* __restrict__ offsets,
    int4* __restrict__ edge_pack)
{
    const int p    = blockIdx.x & 7;
    const int blk  = blockIdx.x >> 3;                 // 0..SBLK-1
    const int base = blk * 256 + threadIdx.x;         // 0..STHREADS-1
    const int rlo  = p * R_PER_P;
    const int rhi  = rlo + R_PER_P;

    #pragma unroll
    for (int k = 0; k < 8; ++k) {
        const int e = base + k * STHREADS;
        if (e < N_NN_C) {
            const int r = receivers[e];
            if (r >= rlo && r < rhi) {
                const int dst = offsets[r] + rank[e];
                edge_pack[dst] = make_int4(e, senders[e], r, 0);
            }
        }
    }
}

// ---------------------------------------------------------------------------
// Fused CSR edge compute + in-block segmented reduction, with WAVE-COOPERATIVE
// row gather. Phase G: 8 lanes per row load e_embed (bf16-packed in flight)
// and proj_s rows coalesced into LDS — 2 txns/row instead of 8 (the R7-R9
// request-rate wall: warm-L3 replays ran at identical time => txn-bound).
// Phase C: thread t reads ITS row from LDS, single-shot math as before.
// Msg staging reuses the ev LDS region. Straddling segments atomicAdd.
// ---------------------------------------------------------------------------
__global__ __launch_bounds__(256) void fused_csr_kernel(
    const float* __restrict__ proj,      // [2][N_NUC][MSG]
    const float* __restrict__ e_embed,   // [N_NN][MSG] f32, original order
    const int4*  __restrict__ edge_pack, // [N_NN] (e, s, r, 0) CSR order
    const int*   __restrict__ offsets,   // [N_NUC+1]
    const float* __restrict__ ln_scale,
    const float* __restrict__ ln_bias,
    const float* __restrict__ W_e,       // [MSG][MSG]
    float*       __restrict__ msg)       // [N_NUC][MSG], pre-zeroed
{
    __shared__ float    lds_ps[256 * PS_STR];   // 36864 B (proj_s rows, f32)
    __shared__ unsigned lds_ev[256 * EV_STR];   // 20480 B (e rows, bf16x2) -> reused for msg staging
    __shared__ int      lds_e[256], lds_s[256], lds_r[256];

    const int t  = threadIdx.x;
    const int B0 = blockIdx.x * 256;     // first slot of this block

    // ---- phase 0: indices to LDS ----
    const int4 pk = edge_pack[B0 + t];
    lds_e[t] = pk.x; lds_s[t] = pk.y; lds_r[t] = pk.z;
    const int r = pk.z;
    __syncthreads();

    // ---- phase G: cooperative gather (8 lanes/row, 8 passes) ----
    {
        const int rowb = t >> 3;          // 0..31
        const int sub  = t & 7;           // float4 index within row
        #pragma unroll
        for (int p = 0; p < 8; ++p) {
            const int i  = p * 32 + rowb;
            const int ei = lds_e[i];
            const int si = lds_s[i];
            const float4 ev4 = *reinterpret_cast<const float4*>(e_embed + (size_t)ei * MSG_C + sub * 4);
            const float4 ps4 = *reinterpret_cast<const float4*>(proj    + (size_t)si * MSG_C + sub * 4);
            const unsigned w0 = pack_bf16x2(ev4.x, ev4.y);
            const unsigned w1 = pack_bf16x2(ev4.z, ev4.w);
            *reinterpret_cast<uint2*>(&lds_ev[i * EV_STR + sub * 2])  = make_uint2(w0, w1);
            *reinterpret_cast<float4*>(&lds_ps[i * PS_STR + sub * 4]) = ps4;
        }
    }
    __syncthreads();

    // ---- phase C: own rows -> registers ----
    float ev[MSG_C], x[MSG_C];
    {
        #pragma unroll
        for (int q = 0; q < 4; ++q) {
            const uint4 w = *reinterpret_cast<const uint4*>(&lds_ev[t * EV_STR + q * 4]);
            ev[8*q+0] = __uint_as_float(w.x << 16);
            ev[8*q+1] = __uint_as_float(w.x & 0xFFFF0000u);
            ev[8*q+2] = __uint_as_float(w.y << 16);
            ev[8*q+3] = __uint_as_float(w.y & 0xFFFF0000u);
            ev[8*q+4] = __uint_as_float(w.z << 16);
            ev[8*q+5] = __uint_as_float(w.z & 0xFFFF0000u);
            ev[8*q+6] = __uint_as_float(w.w << 16);
            ev[8*q+7] = __uint_as_float(w.w & 0xFFFF0000u);
        }
        const float4* pq = reinterpret_cast<const float4*>(proj + (size_t)(N_NUC_C + r) * MSG_C);
        #pragma unroll
        for (int q = 0; q < 8; ++q) {
            const float4 a = *reinterpret_cast<const float4*>(&lds_ps[t * PS_STR + q * 4]);
            const float4 b = pq[q];
            x[4*q+0] = a.x + b.x; x[4*q+1] = a.y + b.y;
            x[4*q+2] = a.z + b.z; x[4*q+3] = a.w + b.w;
        }
    }
    __syncthreads();   // lds_ev/lds_ps reads done; safe to overwrite below

    // gate = e @ W_e (wave-uniform W_e -> scalar operands)
    float g[MSG_C];
    #pragma unroll
    for (int c = 0; c < MSG_C; ++c) g[c] = 0.0f;
    #pragma unroll
    for (int k = 0; k < MSG_C; ++k) {
        const float ek = ev[k];
        #pragma unroll
        for (int c = 0; c < MSG_C; ++c)
            g[c] = fmaf(ek, W_e[k * MSG_C + c], g[c]);
    }

    // LayerNorm + SiLU, write packed bf16 message into the ev region
    float mu = 0.0f;
    #pragma unroll
    for (int c = 0; c < MSG_C; ++c) mu += x[c];
    mu *= (1.0f / MSG_C);
    float var = 0.0f;
    #pragma unroll
    for (int c = 0; c < MSG_C; ++c) { const float d = x[c] - mu; var = fmaf(d, d, var); }
    var *= (1.0f / MSG_C);
    const float rs = rsqrtf(var + 1e-6f);

    unsigned* orow = &lds_ev[t * 17];   // msg staging: stride 17 (odd -> conflict-free)
    #pragma unroll
    for (int i = 0; i < 16; ++i) {
        const int c0_ = 2*i, c1_ = 2*i + 1;
        const float y0 = (x[c0_] - mu) * rs * ln_scale[c0_] + ln_bias[c0_];
        const float y1 = (x[c1_] - mu) * rs * ln_scale[c1_] + ln_bias[c1_];
        orow[i] = pack_bf16x2(silu_f(y0) * g[c0_], silu_f(y1) * g[c1_]);
    }

    __syncthreads();

    // ---- phase R: segmented reduction over receivers in this block ----
    const int r0 = lds_r[0];
    const int r1 = lds_r[255];
    const int total = (r1 - r0 + 1) << 5;   // (#receivers) * 32 channels

    for (int p = t; p < total; p += 256) {
        const int n  = r0 + (p >> 5);
        const int ch = p & 31;
        int b  = offsets[n];
        int en = offsets[n + 1];
        const bool interior = (b >= B0) && (en <= B0 + 256);
        if (b < B0) b = B0;
        if (en > B0 + 256) en = B0 + 256;

        const int dw  = ch >> 1;
        const bool hi = (ch & 1);
        float sum = 0.0f;
        for (int q = b - B0; q < en - B0; ++q) {
            const unsigned u = lds_ev[q * 17 + dw];
            sum += __uint_as_float(hi ? (u & 0xFFFF0000u) : (u << 16));
        }

        float* dst = msg + (size_t)n * MSG_C + ch;
        if (interior)       *dst = sum;          // sole owner (incl. empty = 0)
        else if (en > b)    atomicAdd(dst, sum); // straddling segment part
    }
}

// ---------------------------------------------------------------------------
// Fallback (tiny ws): R1 atomic edge kernel
// ---------------------------------------------------------------------------
__global__ __launch_bounds__(256) void edge_kernel(
    const float* __restrict__ proj, const float* __restrict__ e_embed,
    const int* __restrict__ senders, const int* __restrict__ receivers,
    const float* __restrict__ ln_scale, const float* __restrict__ ln_bias,
    const float* __restrict__ W_e, float* __restrict__ msg)
{
    const int e = blockIdx.x * blockDim.x + threadIdx.x;
    if (e >= N_NN_C) return;
    const int s = senders[e];
    const int r = receivers[e];
    const float4* ps = reinterpret_cast<const float4*>(proj + (size_t)s * MSG_C);
    const float4* pq = reinterpret_cast<const float4*>(proj + (size_t)(N_NUC_C + r) * MSG_C);
    float x[MSG_C];
    #pragma unroll
    for (int q = 0; q < 8; ++q) {
        const float4 a = ps[q];
        const float4 b = pq[q];
        x[4*q+0] = a.x + b.x; x[4*q+1] = a.y + b.y;
        x[4*q+2] = a.z + b.z; x[4*q+3] = a.w + b.w;
    }
    float mu = 0.0f;
    #pragma unroll
    for (int c = 0; c < MSG_C; ++c) mu += x[c];
    mu *= (1.0f / MSG_C);
    float var = 0.0f;
    #pragma unroll
    for (int c = 0; c < MSG_C; ++c) { const float d = x[c] - mu; var = fmaf(d, d, var); }
    var *= (1.0f / MSG_C);
    const float rs = rsqrtf(var + 1e-6f);
    #pragma unroll
    for (int c = 0; c < MSG_C; ++c) {
        const float y = (x[c] - mu) * rs * ln_scale[c] + ln_bias[c];
        x[c] = silu_f(y);
    }
    float ev[MSG_C];
    const float4* ee = reinterpret_cast<const float4*>(e_embed + (size_t)e * MSG_C);
    #pragma unroll
    for (int q = 0; q < 8; ++q) {
        const float4 v = ee[q];
        ev[4*q+0] = v.x; ev[4*q+1] = v.y; ev[4*q+2] = v.z; ev[4*q+3] = v.w;
    }
    float g[MSG_C];
    #pragma unroll
    for (int c = 0; c < MSG_C; ++c) g[c] = 0.0f;
    #pragma unroll
    for (int k = 0; k < MSG_C; ++k) {
        const float ek = ev[k];
        #pragma unroll
        for (int c = 0; c < MSG_C; ++c) g[c] = fmaf(ek, W_e[k * MSG_C + c], g[c]);
    }
    float* mrow = msg + (size_t)r * MSG_C;
    #pragma unroll
    for (int c = 0; c < MSG_C; ++c) atomicAdd(mrow + c, x[c] * g[c]);
}

// ---------------------------------------------------------------------------
// Kernel C: out[n][j] = silu( (msg[n] . W_out[:,j]) * norm[n] )
// ---------------------------------------------------------------------------
__global__ __launch_bounds__(256) void out_kernel(
    const float* __restrict__ msg, const float* __restrict__ norm,
    const float* __restrict__ W_out, float* __restrict__ out)
{
    const int j     = threadIdx.x & (OUT_C - 1);
    const int local = threadIdx.x >> 7;

    float w[MSG_C];
    #pragma unroll
    for (int k = 0; k < MSG_C; ++k) w[k] = W_out[k * OUT_C + j];

    for (int n = blockIdx.x * 2 + local; n < N_NUC_C; n += gridDim.x * 2) {
        const float4* m4 = reinterpret_cast<const float4*>(msg + (size_t)n * MSG_C);
        float acc = 0.0f;
        #pragma unroll
        for (int q = 0; q < 8; ++q) {
            const float4 mv = m4[q];
            acc = fmaf(mv.x, w[4*q+0], acc);
            acc = fmaf(mv.y, w[4*q+1], acc);
            acc = fmaf(mv.z, w[4*q+2], acc);
            acc = fmaf(mv.w, w[4*q+3], acc);
        }
        acc *= norm[n];
        out[(size_t)n * OUT_C + j] = silu_f(acc);
    }
}

extern "C" void kernel_launch(void* const* d_in, const int* in_sizes, int n_in,
                              void* d_out, int out_size, void* d_ws, size_t ws_size,
                              hipStream_t stream) {
    const float* s_embed   = (const float*)d_in[0];
    const float* r_embed   = (const float*)d_in[1];
    const float* e_embed   = (const float*)d_in[2];
    const float* norm      = (const float*)d_in[3];
    const int*   senders   = (const int*)d_in[4];
    const int*   receivers = (const int*)d_in[5];
    const float* W_s       = (const float*)d_in[6];
    const float* b_s       = (const float*)d_in[7];
    const float* W_r       = (const float*)d_in[8];
    const float* b_r       = (const float*)d_in[9];
    const float* ln_scale  = (const float*)d_in[10];
    const float* ln_bias   = (const float*)d_in[11];
    const float* W_e       = (const float*)d_in[12];
    const float* W_out     = (const float*)d_in[13];
    float* out = (float*)d_out;

    char* ws = (char*)d_ws;
    size_t off = 0;
    auto alloc = [&](size_t bytes) { char* p = ws + off; off += (bytes + 255) & ~(size_t)255; return p; };

    float* proj      = (float*)alloc((size_t)2 * N_NUC_C * MSG_C * 4); // 25.6 MB
    float* msg       = (float*)alloc((size_t)N_NUC_C * MSG_C * 4);     // 12.8 MB
    const size_t off_min = off;                                        // 38.4 MB
    int*   cnt       = (int*)  alloc((size_t)N_NUC_C * 4);
    int*   excl      = (int*)  alloc((size_t)N_NUC_C * 4);
    int*   offsets   = (int*)  alloc((size_t)(N_NUC_C + 1) * 4);
    int*   blockTot  = (int*)  alloc(128 * 4);
    int*   blockOff  = (int*)  alloc(128 * 4);
    int*   rank      = (int*)  alloc((size_t)N_NN_C * 4);              // 6.4 MB
    int4*  edge_pack = (int4*) alloc((size_t)N_NN_C * 16);             // 25.6 MB
    const size_t off_full = off;                                       // ~72 MB

    dim3 pgrid((N_NUC_C + 255) / 256, 4);
    proj_kernel<<<pgrid, 256, 0, stream>>>(s_embed, r_embed, W_s, b_s, W_r, b_r, proj);

    if (off_full <= ws_size) {
        // --- CSR (1 atomic pass) + partition-local scatter +
        //     fused edge-compute/in-block-reduce w/ cooperative gather ---
        hipMemsetAsync(cnt, 0, (size_t)N_NUC_C * 4, stream);
        hipMemsetAsync(msg, 0, (size_t)N_NUC_C * MSG_C * 4, stream);
        rank_kernel<<<(N_NN_C + 255) / 256, 256, 0, stream>>>(receivers, cnt, rank);
        scan1_kernel<<<NB1, 256, 0, stream>>>(cnt, excl, blockTot);
        scan2_kernel<<<1, 128, 0, stream>>>(blockTot, blockOff);
        scan3_kernel<<<(N_NUC_C + 255) / 256, 256, 0, stream>>>(excl, blockOff, offsets);
        scatter_pack8_kernel<<<NPART * SBLK, 256, 0, stream>>>(
            senders, receivers, rank, offsets, edge_pack);
        fused_csr_kernel<<<N_NN_C / 256, 256, 0, stream>>>(
            proj, e_embed, edge_pack, offsets, ln_scale, ln_bias, W_e, msg);
    } else if (off_min <= ws_size) {
        // --- fallback: R1 atomic path ---
        hipMemsetAsync(msg, 0, (size_t)N_NUC_C * MSG_C * 4, stream);
        edge_kernel<<<(N_NN_C + 255) / 256, 256, 0, stream>>>(
            proj, e_embed, senders, receivers, ln_scale, ln_bias, W_e, msg);
    }

    out_kernel<<<2048, 256, 0, stream>>>(msg, norm, W_out, out);
}

// Round 11
// 389.507 us; speedup vs baseline: 1.0315x; 1.0315x over previous
//
#include <hip/hip_runtime.h>
#include <hip/hip_bf16.h>
#include <math.h>

#define N_NUC_C 100000
#define N_NN_C  1600000
#define EMB_C   128
#define MSG_C   32
#define OUT_C   128
#define NB1     98   // ceil(N_NUC / 1024) for the scan
#define NPART   8
#define R_PER_P (N_NUC_C / NPART)          // 12500 receivers per partition
#define SBLK    784                        // blocks per partition in scatter/count
#define STHREADS (SBLK * 256)              // 200704 threads per partition
#define LDS_USTR 17                        // uint row stride (16 packed + 1 pad, odd -> conflict-free)

__device__ __forceinline__ float silu_f(float y) {
    return y / (1.0f + __expf(-y));
}

// round-to-nearest-even f32->bf16, packed pair (a -> low 16, b -> high 16)
__device__ __forceinline__ unsigned pack_bf16x2(float a, float b) {
    unsigned ua = __float_as_uint(a); ua += 0x7FFFu + ((ua >> 16) & 1u);
    unsigned ub = __float_as_uint(b); ub += 0x7FFFu + ((ub >> 16) & 1u);
    return (ua >> 16) | (ub & 0xFFFF0000u);
}

// ---------------------------------------------------------------------------
// Kernel A: node projections  proj[pr][n][c] = embed[n] @ W + b
// ---------------------------------------------------------------------------
__global__ __launch_bounds__(256) void proj_kernel(
    const float* __restrict__ s_embed, const float* __restrict__ r_embed,
    const float* __restrict__ W_s, const float* __restrict__ b_s,
    const float* __restrict__ W_r, const float* __restrict__ b_r,
    float* __restrict__ proj /* [2][N_NUC][MSG] */)
{
    const int n   = blockIdx.x * blockDim.x + threadIdx.x;
    const int sub = blockIdx.y;       // 0..3
    const int pr  = sub >> 1;
    const int c0  = (sub & 1) * 16;
    if (n >= N_NUC_C) return;

    const float* __restrict__ src = pr ? r_embed : s_embed;
    const float* __restrict__ W   = pr ? W_r : W_s;
    const float* __restrict__ b   = pr ? b_r : b_s;
    float* __restrict__ dst = proj + (size_t)pr * N_NUC_C * MSG_C;

    float acc[16];
    #pragma unroll
    for (int i = 0; i < 16; ++i) acc[i] = b[c0 + i];

    const float* row = src + (size_t)n * EMB_C;
    #pragma unroll 4
    for (int k = 0; k < EMB_C; k += 4) {
        const float4 rv = *reinterpret_cast<const float4*>(row + k);
        #pragma unroll
        for (int i = 0; i < 16; ++i) {
            acc[i] = fmaf(rv.x, W[(k + 0) * MSG_C + c0 + i], acc[i]);
            acc[i] = fmaf(rv.y, W[(k + 1) * MSG_C + c0 + i], acc[i]);
            acc[i] = fmaf(rv.z, W[(k + 2) * MSG_C + c0 + i], acc[i]);
            acc[i] = fmaf(rv.w, W[(k + 3) * MSG_C + c0 + i], acc[i]);
        }
    }

    float4* d = reinterpret_cast<float4*>(dst + (size_t)n * MSG_C + c0);
    d[0] = make_float4(acc[0],  acc[1],  acc[2],  acc[3]);
    d[1] = make_float4(acc[4],  acc[5],  acc[6],  acc[7]);
    d[2] = make_float4(acc[8],  acc[9],  acc[10], acc[11]);
    d[3] = make_float4(acc[12], acc[13], acc[14], acc[15]);
}

// ---------------------------------------------------------------------------
// Partition-local count: blocks with blockIdx%8==p scan ALL receivers
// (coalesced, L2/L3-resident) and count only r in range p. Each 50 KB cnt
// slice is touched by one partition's clustered blocks -> XCD-local atomics
// instead of cross-fabric (the ~80 us rank pass this replaces).
// ---------------------------------------------------------------------------
__global__ __launch_bounds__(256) void count8_kernel(
    const int* __restrict__ receivers, int* __restrict__ cnt)
{
    const int p    = blockIdx.x & 7;
    const int blk  = blockIdx.x >> 3;
    const int base = blk * 256 + threadIdx.x;
    const int rlo  = p * R_PER_P;
    const int rhi  = rlo + R_PER_P;

    #pragma unroll
    for (int k = 0; k < 8; ++k) {
        const int e = base + k * STHREADS;
        if (e < N_NN_C) {
            const int r = receivers[e];
            if (r >= rlo && r < rhi)
                atomicAdd(&cnt[r], 1);
        }
    }
}

// Exclusive scan of cnt[N_NUC] -> offsets (+ cursor copy). Three tiny kernels.
__global__ __launch_bounds__(256) void scan1_kernel(
    const int* __restrict__ cnt, int* __restrict__ excl, int* __restrict__ blockTot)
{
    __shared__ int waveTot[4];
    const int t = threadIdx.x, b = blockIdx.x;
    const int lane = t & 63, wid = t >> 6;
    const int base = b * 1024 + t * 4;

    int d0 = (base + 0 < N_NUC_C) ? cnt[base + 0] : 0;
    int d1 = (base + 1 < N_NUC_C) ? cnt[base + 1] : 0;
    int d2 = (base + 2 < N_NUC_C) ? cnt[base + 2] : 0;
    int d3 = (base + 3 < N_NUC_C) ? cnt[base + 3] : 0;
    const int s = d0 + d1 + d2 + d3;

    int incl = s;
    #pragma unroll
    for (int off = 1; off < 64; off <<= 1) {
        int v = __shfl_up(incl, off);
        if (lane >= off) incl += v;
    }
    const int wexcl = incl - s;
    if (lane == 63) waveTot[wid] = incl;
    __syncthreads();
    int wbase = 0;
    for (int w = 0; w < wid; ++w) wbase += waveTot[w];
    const int e0 = wbase + wexcl;

    if (base + 0 < N_NUC_C) excl[base + 0] = e0;
    if (base + 1 < N_NUC_C) excl[base + 1] = e0 + d0;
    if (base + 2 < N_NUC_C) excl[base + 2] = e0 + d0 + d1;
    if (base + 3 < N_NUC_C) excl[base + 3] = e0 + d0 + d1 + d2;
    if (t == 255) blockTot[b] = wbase + incl;
}

__global__ __launch_bounds__(128) void scan2_kernel(
    const int* __restrict__ blockTot, int* __restrict__ blockOff)
{
    __shared__ int sh[128];
    const int t = threadIdx.x;
    const int v = (t < NB1) ? blockTot[t] : 0;
    sh[t] = v;
    __syncthreads();
    #pragma unroll
    for (int off = 1; off < 128; off <<= 1) {
        int x = 0;
        if (t >= off) x = sh[t - off];
        __syncthreads();
        sh[t] += x;
        __syncthreads();
    }
    if (t < NB1) blockOff[t] = sh[t] - v;
}

__global__ __launch_bounds__(256) void scan3_kernel(
    const int* __restrict__ excl, const int* __restrict__ blockOff,
    int* __restrict__ offsets, int* __restrict__ cursor)
{
    const int n = blockIdx.x * blockDim.x + threadIdx.x;
    if (n < N_NUC_C) {
        const int v = excl[n] + blockOff[n >> 10];
        offsets[n] = v;
        cursor[n]  = v;
    }
    if (n == 0) offsets[N_NUC_C] = N_NN_C;
}

// ---------------------------------------------------------------------------
// Partition-local scatter with XCD-local cursor atomics (R6-proven): blocks
// with blockIdx%8==p scan all edges and scatter only r in range p to
// dst = atomicAdd(&cursor[r],1). cursor slice + pack region are partition-
// clustered -> L2-local atomics + write coalescing. No rank array/pass.
// ---------------------------------------------------------------------------
__global__ __launch_bounds__(256) void scatter_pack8_kernel(
    const int* __restrict__ senders, const int* __restrict__ receivers,
    int* __restrict__ cursor, int4* __restrict__ edge_pack)
{
    const int p    = blockIdx.x & 7;
    const int blk  = blockIdx.x >> 3;                 // 0..SBLK-1
    const int base = blk * 256 + threadIdx.x;         // 0..STHREADS-1
    const int rlo  = p * R_PER_P;
    const int rhi  = rlo + R_PER_P;

    #pragma unroll
    for (int k = 0; k < 8; ++k) {
        const int e = base + k * STHREADS;
        if (e < N_NN_C) {
            const int r = receivers[e];
            if (r >= rlo && r < rhi) {
                const int dst = atomicAdd(&cursor[r], 1);
                edge_pack[dst] = make_int4(e, senders[e], r, 0);
            }
        }
    }
}

// ---------------------------------------------------------------------------
// Fused CSR edge compute + in-block segmented reduction (R7-best version).
// Block = 256 consecutive CSR slots. Thread = one slot, single-shot math.
// Messages staged in LDS bf16x2 (uint[256][17], conflict-free). Reduce in f32.
// ---------------------------------------------------------------------------
__global__ __launch_bounds__(256) void fused_csr_kernel(
    const float* __restrict__ proj,      // [2][N_NUC][MSG]
    const float* __restrict__ e_embed,   // [N_NN][MSG]
    const int4*  __restrict__ edge_pack, // [N_NN] (e, s, r, 0) CSR order
    const int*   __restrict__ offsets,   // [N_NUC+1]
    const float* __restrict__ ln_scale,
    const float* __restrict__ ln_bias,
    const float* __restrict__ W_e,       // [MSG][MSG]
    float*       __restrict__ msg)       // [N_NUC][MSG], pre-zeroed
{
    __shared__ unsigned lds_u[256 * LDS_USTR];
    __shared__ int      lds_r[256];

    const int t  = threadIdx.x;
    const int B0 = blockIdx.x * 256;     // first slot of this block

    // ---- phase 1: per-edge message (single-shot, straight-line) ----
    const int4 pk = edge_pack[B0 + t];
    const int e = pk.x, s = pk.y, r = pk.z;
    lds_r[t] = r;

    const float4* ee = reinterpret_cast<const float4*>(e_embed + (size_t)e * MSG_C);
    const float4* ps = reinterpret_cast<const float4*>(proj + (size_t)s * MSG_C);
    const float4* pq = reinterpret_cast<const float4*>(proj + (size_t)(N_NUC_C + r) * MSG_C);

    float ev[MSG_C], x[MSG_C];
    #pragma unroll
    for (int q = 0; q < 8; ++q) {
        const float4 v = ee[q];
        ev[4*q+0] = v.x; ev[4*q+1] = v.y; ev[4*q+2] = v.z; ev[4*q+3] = v.w;
    }
    #pragma unroll
    for (int q = 0; q < 8; ++q) {
        const float4 a = ps[q];
        const float4 b = pq[q];
        x[4*q+0] = a.x + b.x; x[4*q+1] = a.y + b.y;
        x[4*q+2] = a.z + b.z; x[4*q+3] = a.w + b.w;
    }

    // gate = e @ W_e (wave-uniform W_e -> scalar operands)
    float g[MSG_C];
    #pragma unroll
    for (int c = 0; c < MSG_C; ++c) g[c] = 0.0f;
    #pragma unroll
    for (int k = 0; k < MSG_C; ++k) {
        const float ek = ev[k];
        #pragma unroll
        for (int c = 0; c < MSG_C; ++c)
            g[c] = fmaf(ek, W_e[k * MSG_C + c], g[c]);
    }

    // LayerNorm + SiLU, write packed bf16 message to LDS
    float mu = 0.0f;
    #pragma unroll
    for (int c = 0; c < MSG_C; ++c) mu += x[c];
    mu *= (1.0f / MSG_C);
    float var = 0.0f;
    #pragma unroll
    for (int c = 0; c < MSG_C; ++c) { const float d = x[c] - mu; var = fmaf(d, d, var); }
    var *= (1.0f / MSG_C);
    const float rs = rsqrtf(var + 1e-6f);

    unsigned* orow = &lds_u[t * LDS_USTR];
    #pragma unroll
    for (int i = 0; i < 16; ++i) {
        const int c0_ = 2*i, c1_ = 2*i + 1;
        const float y0 = (x[c0_] - mu) * rs * ln_scale[c0_] + ln_bias[c0_];
        const float y1 = (x[c1_] - mu) * rs * ln_scale[c1_] + ln_bias[c1_];
        orow[i] = pack_bf16x2(silu_f(y0) * g[c0_], silu_f(y1) * g[c1_]);
    }

    __syncthreads();

    // ---- phase 2: segmented reduction over receivers in this block ----
    const int r0 = lds_r[0];
    const int r1 = lds_r[255];
    const int total = (r1 - r0 + 1) << 5;   // (#receivers) * 32 channels

    for (int p = t; p < total; p += 256) {
        const int n  = r0 + (p >> 5);
        const int ch = p & 31;
        int b  = offsets[n];
        int en = offsets[n + 1];
        const bool interior = (b >= B0) && (en <= B0 + 256);
        if (b < B0) b = B0;
        if (en > B0 + 256) en = B0 + 256;

        const int dw  = ch >> 1;
        const bool hi = (ch & 1);
        float sum = 0.0f;
        for (int q = b - B0; q < en - B0; ++q) {
            const unsigned u = lds_u[q * LDS_USTR + dw];
            sum += __uint_as_float(hi ? (u & 0xFFFF0000u) : (u << 16));
        }

        float* dst = msg + (size_t)n * MSG_C + ch;
        if (interior)       *dst = sum;          // sole owner (incl. empty = 0)
        else if (en > b)    atomicAdd(dst, sum); // straddling segment part
    }
}

// ---------------------------------------------------------------------------
// Fallback (tiny ws): R1 atomic edge kernel
// ---------------------------------------------------------------------------
__global__ __launch_bounds__(256) void edge_kernel(
    const float* __restrict__ proj, const float* __restrict__ e_embed,
    const int* __restrict__ senders, const int* __restrict__ receivers,
    const float* __restrict__ ln_scale, const float* __restrict__ ln_bias,
    const float* __restrict__ W_e, float* __restrict__ msg)
{
    const int e = blockIdx.x * blockDim.x + threadIdx.x;
    if (e >= N_NN_C) return;
    const int s = senders[e];
    const int r = receivers[e];
    const float4* ps = reinterpret_cast<const float4*>(proj + (size_t)s * MSG_C);
    const float4* pq = reinterpret_cast<const float4*>(proj + (size_t)(N_NUC_C + r) * MSG_C);
    float x[MSG_C];
    #pragma unroll
    for (int q = 0; q < 8; ++q) {
        const float4 a = ps[q];
        const float4 b = pq[q];
        x[4*q+0] = a.x + b.x; x[4*q+1] = a.y + b.y;
        x[4*q+2] = a.z + b.z; x[4*q+3] = a.w + b.w;
    }
    float mu = 0.0f;
    #pragma unroll
    for (int c = 0; c < MSG_C; ++c) mu += x[c];
    mu *= (1.0f / MSG_C);
    float var = 0.0f;
    #pragma unroll
    for (int c = 0; c < MSG_C; ++c) { const float d = x[c] - mu; var = fmaf(d, d, var); }
    var *= (1.0f / MSG_C);
    const float rs = rsqrtf(var + 1e-6f);
    #pragma unroll
    for (int c = 0; c < MSG_C; ++c) {
        const float y = (x[c] - mu) * rs * ln_scale[c] + ln_bias[c];
        x[c] = silu_f(y);
    }
    float ev[MSG_C];
    const float4* ee = reinterpret_cast<const float4*>(e_embed + (size_t)e * MSG_C);
    #pragma unroll
    for (int q = 0; q < 8; ++q) {
        const float4 v = ee[q];
        ev[4*q+0] = v.x; ev[4*q+1] = v.y; ev[4*q+2] = v.z; ev[4*q+3] = v.w;
    }
    float g[MSG_C];
    #pragma unroll
    for (int c = 0; c < MSG_C; ++c) g[c] = 0.0f;
    #pragma unroll
    for (int k = 0; k < MSG_C; ++k) {
        const float ek = ev[k];
        #pragma unroll
        for (int c = 0; c < MSG_C; ++c) g[c] = fmaf(ek, W_e[k * MSG_C + c], g[c]);
    }
    float* mrow = msg + (size_t)r * MSG_C;
    #pragma unroll
    for (int c = 0; c < MSG_C; ++c) atomicAdd(mrow + c, x[c] * g[c]);
}

// ---------------------------------------------------------------------------
// Kernel C: out[n][j] = silu( (msg[n] . W_out[:,j]) * norm[n] )
// ---------------------------------------------------------------------------
__global__ __launch_bounds__(256) void out_kernel(
    const float* __restrict__ msg, const float* __restrict__ norm,
    const float* __restrict__ W_out, float* __restrict__ out)
{
    const int j     = threadIdx.x & (OUT_C - 1);
    const int local = threadIdx.x >> 7;

    float w[MSG_C];
    #pragma unroll
    for (int k = 0; k < MSG_C; ++k) w[k] = W_out[k * OUT_C + j];

    for (int n = blockIdx.x * 2 + local; n < N_NUC_C; n += gridDim.x * 2) {
        const float4* m4 = reinterpret_cast<const float4*>(msg + (size_t)n * MSG_C);
        float acc = 0.0f;
        #pragma unroll
        for (int q = 0; q < 8; ++q) {
            const float4 mv = m4[q];
            acc = fmaf(mv.x, w[4*q+0], acc);
            acc = fmaf(mv.y, w[4*q+1], acc);
            acc = fmaf(mv.z, w[4*q+2], acc);
            acc = fmaf(mv.w, w[4*q+3], acc);
        }
        acc *= norm[n];
        out[(size_t)n * OUT_C + j] = silu_f(acc);
    }
}

extern "C" void kernel_launch(void* const* d_in, const int* in_sizes, int n_in,
                              void* d_out, int out_size, void* d_ws, size_t ws_size,
                              hipStream_t stream) {
    const float* s_embed   = (const float*)d_in[0];
    const float* r_embed   = (const float*)d_in[1];
    const float* e_embed   = (const float*)d_in[2];
    const float* norm      = (const float*)d_in[3];
    const int*   senders   = (const int*)d_in[4];
    const int*   receivers = (const int*)d_in[5];
    const float* W_s       = (const float*)d_in[6];
    const float* b_s       = (const float*)d_in[7];
    const float* W_r       = (const float*)d_in[8];
    const float* b_r       = (const float*)d_in[9];
    const float* ln_scale  = (const float*)d_in[10];
    const float* ln_bias   = (const float*)d_in[11];
    const float* W_e       = (const float*)d_in[12];
    const float* W_out     = (const float*)d_in[13];
    float* out = (float*)d_out;

    char* ws = (char*)d_ws;
    size_t off = 0;
    auto alloc = [&](size_t bytes) { char* p = ws + off; off += (bytes + 255) & ~(size_t)255; return p; };

    float* proj      = (float*)alloc((size_t)2 * N_NUC_C * MSG_C * 4); // 25.6 MB
    float* msg       = (float*)alloc((size_t)N_NUC_C * MSG_C * 4);     // 12.8 MB
    const size_t off_min = off;                                        // 38.4 MB
    int*   cnt       = (int*)  alloc((size_t)N_NUC_C * 4);
    int*   excl      = (int*)  alloc((size_t)N_NUC_C * 4);
    int*   offsets   = (int*)  alloc((size_t)(N_NUC_C + 1) * 4);
    int*   cursor    = (int*)  alloc((size_t)N_NUC_C * 4);
    int*   blockTot  = (int*)  alloc(128 * 4);
    int*   blockOff  = (int*)  alloc(128 * 4);
    int4*  edge_pack = (int4*) alloc((size_t)N_NN_C * 16);             // 25.6 MB
    const size_t off_full = off;                                       // ~66 MB

    dim3 pgrid((N_NUC_C + 255) / 256, 4);
    proj_kernel<<<pgrid, 256, 0, stream>>>(s_embed, r_embed, W_s, b_s, W_r, b_r, proj);

    if (off_full <= ws_size) {
        // --- partition-local count (XCD-local atomics) + scan +
        //     partition-local cursor scatter + fused edge-compute/reduce ---
        hipMemsetAsync(cnt, 0, (size_t)N_NUC_C * 4, stream);
        hipMemsetAsync(msg, 0, (size_t)N_NUC_C * MSG_C * 4, stream);
        count8_kernel<<<NPART * SBLK, 256, 0, stream>>>(receivers, cnt);
        scan1_kernel<<<NB1, 256, 0, stream>>>(cnt, excl, blockTot);
        scan2_kernel<<<1, 128, 0, stream>>>(blockTot, blockOff);
        scan3_kernel<<<(N_NUC_C + 255) / 256, 256, 0, stream>>>(excl, blockOff, offsets, cursor);
        scatter_pack8_kernel<<<NPART * SBLK, 256, 0, stream>>>(
            senders, receivers, cursor, edge_pack);
        fused_csr_kernel<<<N_NN_C / 256, 256, 0, stream>>>(
            proj, e_embed, edge_pack, offsets, ln_scale, ln_bias, W_e, msg);
    } else if (off_min <= ws_size) {
        // --- fallback: R1 atomic path ---
        hipMemsetAsync(msg, 0, (size_t)N_NUC_C * MSG_C * 4, stream);
        edge_kernel<<<(N_NN_C + 255) / 256, 256, 0, stream>>>(
            proj, e_embed, senders, receivers, ln_scale, ln_bias, W_e, msg);
    }

    out_kernel<<<2048, 256, 0, stream>>>(msg, norm, W_out, out);
}

// Round 12
// 347.741 us; speedup vs baseline: 1.1554x; 1.1201x over previous
//
#include <hip/hip_runtime.h>
#include <hip/hip_bf16.h>
#include <math.h>

#define N_NUC_C 100000
#define N_NN_C  1600000
#define EMB_C   128
#define MSG_C   32
#define OUT_C   128
#define NB1     98   // ceil(N_NUC / 1024) for the scan
#define NPART   8
#define R_PER_P (N_NUC_C / NPART)          // 12500 receivers per partition
#define SBLK    784                        // blocks per partition in scatter
#define STHREADS (SBLK * 256)              // 200704 threads per partition
#define LDS_USTR 17                        // uint row stride (16 packed + 1 pad, odd -> conflict-free)

typedef __attribute__((ext_vector_type(8))) short bf16x8;
typedef __attribute__((ext_vector_type(4))) float f32x4;

__device__ __forceinline__ float silu_f(float y) {
    return y / (1.0f + __expf(-y));
}

// round-to-nearest-even f32->bf16, packed pair (a -> low 16, b -> high 16)
__device__ __forceinline__ unsigned pack_bf16x2(float a, float b) {
    unsigned ua = __float_as_uint(a); ua += 0x7FFFu + ((ua >> 16) & 1u);
    unsigned ub = __float_as_uint(b); ub += 0x7FFFu + ((ub >> 16) & 1u);
    return (ua >> 16) | (ub & 0xFFFF0000u);
}

__device__ __forceinline__ unsigned short bf16_of(float a) {
    unsigned ua = __float_as_uint(a); ua += 0x7FFFu + ((ua >> 16) & 1u);
    return (unsigned short)(ua >> 16);
}

// ---------------------------------------------------------------------------
// Kernel A: node projections  proj[pr][n][c] = embed[n] @ W + b
// ---------------------------------------------------------------------------
__global__ __launch_bounds__(256) void proj_kernel(
    const float* __restrict__ s_embed, const float* __restrict__ r_embed,
    const float* __restrict__ W_s, const float* __restrict__ b_s,
    const float* __restrict__ W_r, const float* __restrict__ b_r,
    float* __restrict__ proj /* [2][N_NUC][MSG] */)
{
    const int n   = blockIdx.x * blockDim.x + threadIdx.x;
    const int sub = blockIdx.y;       // 0..3
    const int pr  = sub >> 1;
    const int c0  = (sub & 1) * 16;
    if (n >= N_NUC_C) return;

    const float* __restrict__ src = pr ? r_embed : s_embed;
    const float* __restrict__ W   = pr ? W_r : W_s;
    const float* __restrict__ b   = pr ? b_r : b_s;
    float* __restrict__ dst = proj + (size_t)pr * N_NUC_C * MSG_C;

    float acc[16];
    #pragma unroll
    for (int i = 0; i < 16; ++i) acc[i] = b[c0 + i];

    const float* row = src + (size_t)n * EMB_C;
    #pragma unroll 4
    for (int k = 0; k < EMB_C; k += 4) {
        const float4 rv = *reinterpret_cast<const float4*>(row + k);
        #pragma unroll
        for (int i = 0; i < 16; ++i) {
            acc[i] = fmaf(rv.x, W[(k + 0) * MSG_C + c0 + i], acc[i]);
            acc[i] = fmaf(rv.y, W[(k + 1) * MSG_C + c0 + i], acc[i]);
            acc[i] = fmaf(rv.z, W[(k + 2) * MSG_C + c0 + i], acc[i]);
            acc[i] = fmaf(rv.w, W[(k + 3) * MSG_C + c0 + i], acc[i]);
        }
    }

    float4* d = reinterpret_cast<float4*>(dst + (size_t)n * MSG_C + c0);
    d[0] = make_float4(acc[0],  acc[1],  acc[2],  acc[3]);
    d[1] = make_float4(acc[4],  acc[5],  acc[6],  acc[7]);
    d[2] = make_float4(acc[8],  acc[9],  acc[10], acc[11]);
    d[3] = make_float4(acc[12], acc[13], acc[14], acc[15]);
}

// ---------------------------------------------------------------------------
// CSR build: single atomic pass — rank[e] = running index within receiver
// ---------------------------------------------------------------------------
__global__ __launch_bounds__(256) void rank_kernel(
    const int* __restrict__ receivers, int* __restrict__ cnt,
    int* __restrict__ rank)
{
    const int e = blockIdx.x * blockDim.x + threadIdx.x;
    if (e >= N_NN_C) return;
    rank[e] = atomicAdd(&cnt[receivers[e]], 1);
}

// Exclusive scan of cnt[N_NUC] -> offsets. Three tiny kernels.
__global__ __launch_bounds__(256) void scan1_kernel(
    const int* __restrict__ cnt, int* __restrict__ excl, int* __restrict__ blockTot)
{
    __shared__ int waveTot[4];
    const int t = threadIdx.x, b = blockIdx.x;
    const int lane = t & 63, wid = t >> 6;
    const int base = b * 1024 + t * 4;

    int d0 = (base + 0 < N_NUC_C) ? cnt[base + 0] : 0;
    int d1 = (base + 1 < N_NUC_C) ? cnt[base + 1] : 0;
    int d2 = (base + 2 < N_NUC_C) ? cnt[base + 2] : 0;
    int d3 = (base + 3 < N_NUC_C) ? cnt[base + 3] : 0;
    const int s = d0 + d1 + d2 + d3;

    int incl = s;
    #pragma unroll
    for (int off = 1; off < 64; off <<= 1) {
        int v = __shfl_up(incl, off);
        if (lane >= off) incl += v;
    }
    const int wexcl = incl - s;
    if (lane == 63) waveTot[wid] = incl;
    __syncthreads();
    int wbase = 0;
    for (int w = 0; w < wid; ++w) wbase += waveTot[w];
    const int e0 = wbase + wexcl;

    if (base + 0 < N_NUC_C) excl[base + 0] = e0;
    if (base + 1 < N_NUC_C) excl[base + 1] = e0 + d0;
    if (base + 2 < N_NUC_C) excl[base + 2] = e0 + d0 + d1;
    if (base + 3 < N_NUC_C) excl[base + 3] = e0 + d0 + d1 + d2;
    if (t == 255) blockTot[b] = wbase + incl;
}

__global__ __launch_bounds__(128) void scan2_kernel(
    const int* __restrict__ blockTot, int* __restrict__ blockOff)
{
    __shared__ int sh[128];
    const int t = threadIdx.x;
    const int v = (t < NB1) ? blockTot[t] : 0;
    sh[t] = v;
    __syncthreads();
    #pragma unroll
    for (int off = 1; off < 128; off <<= 1) {
        int x = 0;
        if (t >= off) x = sh[t - off];
        __syncthreads();
        sh[t] += x;
        __syncthreads();
    }
    if (t < NB1) blockOff[t] = sh[t] - v;
}

__global__ __launch_bounds__(256) void scan3_kernel(
    const int* __restrict__ excl, const int* __restrict__ blockOff,
    int* __restrict__ offsets)
{
    const int n = blockIdx.x * blockDim.x + threadIdx.x;
    if (n < N_NUC_C) offsets[n] = excl[n] + blockOff[n >> 10];
    if (n == 0) offsets[N_NUC_C] = N_NN_C;
}

// ---------------------------------------------------------------------------
// Partition-local ATOMIC-FREE scatter (R7-proven): blocks with blockIdx%8==p
// scan all edges (coalesced) and write int4 (e,s,r,0) to
// dst = offsets[r] + rank[e]. Partition-clustered -> L2 write coalescing.
// ---------------------------------------------------------------------------
__global__ __launch_bounds__(256) void scatter_pack8_kernel(
    const int* __restrict__ senders, const int* __restrict__ receivers,
    const int* __restrict__ rank, const int* __restrict__ offsets,
    int4* __restrict__ edge_pack)
{
    const int p    = blockIdx.x & 7;
    const int blk  = blockIdx.x >> 3;                 // 0..SBLK-1
    const int base = blk * 256 + threadIdx.x;         // 0..STHREADS-1
    const int rlo  = p * R_PER_P;
    const int rhi  = rlo + R_PER_P;

    #pragma unroll
    for (int k = 0; k < 8; ++k) {
        const int e = base + k * STHREADS;
        if (e < N_NN_C) {
            const int r = receivers[e];
            if (r >= rlo && r < rhi) {
                const int dst = offsets[r] + rank[e];
                edge_pack[dst] = make_int4(e, senders[e], r, 0);
            }
        }
    }
}

// ---------------------------------------------------------------------------
// Fused CSR edge compute + in-block segmented reduction, gate via MFMA.
// Per wave: gate[64x32] = ev[64x32] @ W_e[32x32] as 8 x mfma_f32_16x16x32_bf16
// (4 M-tiles x 2 N-tiles, K=32 in one step) — replaces 1024 VALU FMAs/thread.
// ev rows staged bf16 in LDS (stride 17); A-frag: lane holds
// ev[row=mt*16+(lane&15)][k=8*(lane>>4)+i]; B-frag: W_e[k][n=(lane&15)+16*nt];
// C layout (m89-verified): row=(lane>>4)*4+reg, col=lane&15 -> gate staged
// bf16 in LDS, each thread reads its own row back. Rest identical to R7.
// ---------------------------------------------------------------------------
__global__ __launch_bounds__(256) void fused_csr_kernel(
    const float* __restrict__ proj,      // [2][N_NUC][MSG]
    const float* __restrict__ e_embed,   // [N_NN][MSG]
    const int4*  __restrict__ edge_pack, // [N_NN] (e, s, r, 0) CSR order
    const int*   __restrict__ offsets,   // [N_NUC+1]
    const float* __restrict__ ln_scale,
    const float* __restrict__ ln_bias,
    const float* __restrict__ W_e,       // [MSG][MSG]
    float*       __restrict__ msg)       // [N_NUC][MSG], pre-zeroed
{
    __shared__ unsigned lds_ev[256 * LDS_USTR];  // bf16 ev rows -> reused for msg staging
    __shared__ unsigned lds_g [256 * LDS_USTR];  // bf16 gate rows
    __shared__ int      lds_r[256];

    const int t    = threadIdx.x;
    const int lane = t & 63;
    const int wb   = t & ~63;            // wave's first row (0,64,128,192)
    const int B0   = blockIdx.x * 256;   // first CSR slot of this block

    const int4 pk = edge_pack[B0 + t];
    const int e = pk.x, s = pk.y, r = pk.z;
    lds_r[t] = r;

    // ---- stage own ev row to LDS as bf16 ----
    {
        const float4* ee = reinterpret_cast<const float4*>(e_embed + (size_t)e * MSG_C);
        unsigned* evrow = &lds_ev[t * LDS_USTR];
        #pragma unroll
        for (int q = 0; q < 8; ++q) {
            const float4 v = ee[q];
            evrow[2*q+0] = pack_bf16x2(v.x, v.y);
            evrow[2*q+1] = pack_bf16x2(v.z, v.w);
        }
    }

    // ---- B fragments of W_e (bf16): lane holds k=8*(lane>>4)+i, n=lane&15 ----
    bf16x8 bf0, bf1;
    {
        const int kg = (lane >> 4) * 8;
        const int n0 = lane & 15;
        #pragma unroll
        for (int i = 0; i < 8; ++i) {
            bf0[i] = (short)bf16_of(W_e[(kg + i) * MSG_C + n0]);
            bf1[i] = (short)bf16_of(W_e[(kg + i) * MSG_C + 16 + n0]);
        }
    }

    __syncthreads();   // B1: all ev rows staged

    // ---- MFMA: gate = ev @ W_e, write bf16 gate rows to LDS ----
    {
        unsigned short* g16 = reinterpret_cast<unsigned short*>(lds_g);
        #pragma unroll
        for (int mt = 0; mt < 4; ++mt) {
            const int arow = wb + mt * 16 + (lane & 15);
            const unsigned* ar = &lds_ev[arow * LDS_USTR + ((lane >> 4) << 2)];
            const unsigned u0 = ar[0], u1 = ar[1], u2 = ar[2], u3 = ar[3];
            bf16x8 af;
            af[0] = (short)(u0 & 0xFFFFu); af[1] = (short)(u0 >> 16);
            af[2] = (short)(u1 & 0xFFFFu); af[3] = (short)(u1 >> 16);
            af[4] = (short)(u2 & 0xFFFFu); af[5] = (short)(u2 >> 16);
            af[6] = (short)(u3 & 0xFFFFu); af[7] = (short)(u3 >> 16);
            f32x4 z = {0.f, 0.f, 0.f, 0.f};
            const f32x4 a0 = __builtin_amdgcn_mfma_f32_16x16x32_bf16(af, bf0, z, 0, 0, 0);
            const f32x4 a1 = __builtin_amdgcn_mfma_f32_16x16x32_bf16(af, bf1, z, 0, 0, 0);
            const int rbase = wb + mt * 16 + ((lane >> 4) << 2);
            #pragma unroll
            for (int rg = 0; rg < 4; ++rg) {
                g16[(rbase + rg) * (2 * LDS_USTR) + (lane & 15)]      = bf16_of(a0[rg]);
                g16[(rbase + rg) * (2 * LDS_USTR) + 16 + (lane & 15)] = bf16_of(a1[rg]);
            }
        }
    }

    __syncthreads();   // B2: all gate rows written

    // ---- own gate row -> registers ----
    float g[MSG_C];
    {
        const unsigned* gr = &lds_g[t * LDS_USTR];
        #pragma unroll
        for (int j = 0; j < 16; ++j) {
            const unsigned u = gr[j];
            g[2*j]   = __uint_as_float(u << 16);
            g[2*j+1] = __uint_as_float(u & 0xFFFF0000u);
        }
    }

    // ---- x = proj_s + proj_r, LayerNorm + SiLU, msg -> lds_ev (reuse) ----
    const float4* ps = reinterpret_cast<const float4*>(proj + (size_t)s * MSG_C);
    const float4* pq = reinterpret_cast<const float4*>(proj + (size_t)(N_NUC_C + r) * MSG_C);
    float x[MSG_C];
    #pragma unroll
    for (int q = 0; q < 8; ++q) {
        const float4 a = ps[q];
        const float4 b = pq[q];
        x[4*q+0] = a.x + b.x; x[4*q+1] = a.y + b.y;
        x[4*q+2] = a.z + b.z; x[4*q+3] = a.w + b.w;
    }

    float mu = 0.0f;
    #pragma unroll
    for (int c = 0; c < MSG_C; ++c) mu += x[c];
    mu *= (1.0f / MSG_C);
    float var = 0.0f;
    #pragma unroll
    for (int c = 0; c < MSG_C; ++c) { const float d = x[c] - mu; var = fmaf(d, d, var); }
    var *= (1.0f / MSG_C);
    const float rs = rsqrtf(var + 1e-6f);

    unsigned* orow = &lds_ev[t * LDS_USTR];
    #pragma unroll
    for (int i = 0; i < 16; ++i) {
        const int c0_ = 2*i, c1_ = 2*i + 1;
        const float y0 = (x[c0_] - mu) * rs * ln_scale[c0_] + ln_bias[c0_];
        const float y1 = (x[c1_] - mu) * rs * ln_scale[c1_] + ln_bias[c1_];
        orow[i] = pack_bf16x2(silu_f(y0) * g[c0_], silu_f(y1) * g[c1_]);
    }

    __syncthreads();   // B3: all msg rows staged

    // ---- segmented reduction over receivers in this block ----
    const int r0 = lds_r[0];
    const int r1 = lds_r[255];
    const int total = (r1 - r0 + 1) << 5;   // (#receivers) * 32 channels

    for (int p = t; p < total; p += 256) {
        const int n  = r0 + (p >> 5);
        const int ch = p & 31;
        int b  = offsets[n];
        int en = offsets[n + 1];
        const bool interior = (b >= B0) && (en <= B0 + 256);
        if (b < B0) b = B0;
        if (en > B0 + 256) en = B0 + 256;

        const int dw  = ch >> 1;
        const bool hi = (ch & 1);
        float sum = 0.0f;
        for (int q = b - B0; q < en - B0; ++q) {
            const unsigned u = lds_ev[q * LDS_USTR + dw];
            sum += __uint_as_float(hi ? (u & 0xFFFF0000u) : (u << 16));
        }

        float* dst = msg + (size_t)n * MSG_C + ch;
        if (interior)       *dst = sum;          // sole owner (incl. empty = 0)
        else if (en > b)    atomicAdd(dst, sum); // straddling segment part
    }
}

// ---------------------------------------------------------------------------
// Fallback (tiny ws): R1 atomic edge kernel
// ---------------------------------------------------------------------------
__global__ __launch_bounds__(256) void edge_kernel(
    const float* __restrict__ proj, const float* __restrict__ e_embed,
    const int* __restrict__ senders, const int* __restrict__ receivers,
    const float* __restrict__ ln_scale, const float* __restrict__ ln_bias,
    const float* __restrict__ W_e, float* __restrict__ msg)
{
    const int e = blockIdx.x * blockDim.x + threadIdx.x;
    if (e >= N_NN_C) return;
    const int s = senders[e];
    const int r = receivers[e];
    const float4* ps = reinterpret_cast<const float4*>(proj + (size_t)s * MSG_C);
    const float4* pq = reinterpret_cast<const float4*>(proj + (size_t)(N_NUC_C + r) * MSG_C);
    float x[MSG_C];
    #pragma unroll
    for (int q = 0; q < 8; ++q) {
        const float4 a = ps[q];
        const float4 b = pq[q];
        x[4*q+0] = a.x + b.x; x[4*q+1] = a.y + b.y;
        x[4*q+2] = a.z + b.z; x[4*q+3] = a.w + b.w;
    }
    float mu = 0.0f;
    #pragma unroll
    for (int c = 0; c < MSG_C; ++c) mu += x[c];
    mu *= (1.0f / MSG_C);
    float var = 0.0f;
    #pragma unroll
    for (int c = 0; c < MSG_C; ++c) { const float d = x[c] - mu; var = fmaf(d, d, var); }
    var *= (1.0f / MSG_C);
    const float rs = rsqrtf(var + 1e-6f);
    #pragma unroll
    for (int c = 0; c < MSG_C; ++c) {
        const float y = (x[c] - mu) * rs * ln_scale[c] + ln_bias[c];
        x[c] = silu_f(y);
    }
    float ev[MSG_C];
    const float4* ee = reinterpret_cast<const float4*>(e_embed + (size_t)e * MSG_C);
    #pragma unroll
    for (int q = 0; q < 8; ++q) {
        const float4 v = ee[q];
        ev[4*q+0] = v.x; ev[4*q+1] = v.y; ev[4*q+2] = v.z; ev[4*q+3] = v.w;
    }
    float g[MSG_C];
    #pragma unroll
    for (int c = 0; c < MSG_C; ++c) g[c] = 0.0f;
    #pragma unroll
    for (int k = 0; k < MSG_C; ++k) {
        const float ek = ev[k];
        #pragma unroll
        for (int c = 0; c < MSG_C; ++c) g[c] = fmaf(ek, W_e[k * MSG_C + c], g[c]);
    }
    float* mrow = msg + (size_t)r * MSG_C;
    #pragma unroll
    for (int c = 0; c < MSG_C; ++c) atomicAdd(mrow + c, x[c] * g[c]);
}

// ---------------------------------------------------------------------------
// Kernel C: out[n][j] = silu( (msg[n] . W_out[:,j]) * norm[n] )
// ---------------------------------------------------------------------------
__global__ __launch_bounds__(256) void out_kernel(
    const float* __restrict__ msg, const float* __restrict__ norm,
    const float* __restrict__ W_out, float* __restrict__ out)
{
    const int j     = threadIdx.x & (OUT_C - 1);
    const int local = threadIdx.x >> 7;

    float w[MSG_C];
    #pragma unroll
    for (int k = 0; k < MSG_C; ++k) w[k] = W_out[k * OUT_C + j];

    for (int n = blockIdx.x * 2 + local; n < N_NUC_C; n += gridDim.x * 2) {
        const float4* m4 = reinterpret_cast<const float4*>(msg + (size_t)n * MSG_C);
        float acc = 0.0f;
        #pragma unroll
        for (int q = 0; q < 8; ++q) {
            const float4 mv = m4[q];
            acc = fmaf(mv.x, w[4*q+0], acc);
            acc = fmaf(mv.y, w[4*q+1], acc);
            acc = fmaf(mv.z, w[4*q+2], acc);
            acc = fmaf(mv.w, w[4*q+3], acc);
        }
        acc *= norm[n];
        out[(size_t)n * OUT_C + j] = silu_f(acc);
    }
}

extern "C" void kernel_launch(void* const* d_in, const int* in_sizes, int n_in,
                              void* d_out, int out_size, void* d_ws, size_t ws_size,
                              hipStream_t stream) {
    const float* s_embed   = (const float*)d_in[0];
    const float* r_embed   = (const float*)d_in[1];
    const float* e_embed   = (const float*)d_in[2];
    const float* norm      = (const float*)d_in[3];
    const int*   senders   = (const int*)d_in[4];
    const int*   receivers = (const int*)d_in[5];
    const float* W_s       = (const float*)d_in[6];
    const float* b_s       = (const float*)d_in[7];
    const float* W_r       = (const float*)d_in[8];
    const float* b_r       = (const float*)d_in[9];
    const float* ln_scale  = (const float*)d_in[10];
    const float* ln_bias   = (const float*)d_in[11];
    const float* W_e       = (const float*)d_in[12];
    const float* W_out     = (const float*)d_in[13];
    float* out = (float*)d_out;

    char* ws = (char*)d_ws;
    size_t off = 0;
    auto alloc = [&](size_t bytes) { char* p = ws + off; off += (bytes + 255) & ~(size_t)255; return p; };

    float* proj      = (float*)alloc((size_t)2 * N_NUC_C * MSG_C * 4); // 25.6 MB
    float* msg       = (float*)alloc((size_t)N_NUC_C * MSG_C * 4);     // 12.8 MB
    const size_t off_min = off;                                        // 38.4 MB
    int*   cnt       = (int*)  alloc((size_t)N_NUC_C * 4);
    int*   excl      = (int*)  alloc((size_t)N_NUC_C * 4);
    int*   offsets   = (int*)  alloc((size_t)(N_NUC_C + 1) * 4);
    int*   blockTot  = (int*)  alloc(128 * 4);
    int*   blockOff  = (int*)  alloc(128 * 4);
    int*   rank      = (int*)  alloc((size_t)N_NN_C * 4);              // 6.4 MB
    int4*  edge_pack = (int4*) alloc((size_t)N_NN_C * 16);             // 25.6 MB
    const size_t off_full = off;                                       // ~72 MB

    dim3 pgrid((N_NUC_C + 255) / 256, 4);
    proj_kernel<<<pgrid, 256, 0, stream>>>(s_embed, r_embed, W_s, b_s, W_r, b_r, proj);

    if (off_full <= ws_size) {
        // --- R7 CSR build + fused edge-compute/reduce with MFMA gate ---
        hipMemsetAsync(cnt, 0, (size_t)N_NUC_C * 4, stream);
        hipMemsetAsync(msg, 0, (size_t)N_NUC_C * MSG_C * 4, stream);
        rank_kernel<<<(N_NN_C + 255) / 256, 256, 0, stream>>>(receivers, cnt, rank);
        scan1_kernel<<<NB1, 256, 0, stream>>>(cnt, excl, blockTot);
        scan2_kernel<<<1, 128, 0, stream>>>(blockTot, blockOff);
        scan3_kernel<<<(N_NUC_C + 255) / 256, 256, 0, stream>>>(excl, blockOff, offsets);
        scatter_pack8_kernel<<<NPART * SBLK, 256, 0, stream>>>(
            senders, receivers, rank, offsets, edge_pack);
        fused_csr_kernel<<<N_NN_C / 256, 256, 0, stream>>>(
            proj, e_embed, edge_pack, offsets, ln_scale, ln_bias, W_e, msg);
    } else if (off_min <= ws_size) {
        // --- fallback: R1 atomic path ---
        hipMemsetAsync(msg, 0, (size_t)N_NUC_C * MSG_C * 4, stream);
        edge_kernel<<<(N_NN_C + 255) / 256, 256, 0, stream>>>(
            proj, e_embed, senders, receivers, ln_scale, ln_bias, W_e, msg);
    }

    out_kernel<<<2048, 256, 0, stream>>>(msg, norm, W_out, out);
}

// Round 13
// 344.739 us; speedup vs baseline: 1.1655x; 1.0087x over previous
//
#include <hip/hip_runtime.h>
#include <hip/hip_bf16.h>
#include <math.h>

#define N_NUC_C 100000
#define N_NN_C  1600000
#define EMB_C   128
#define MSG_C   32
#define OUT_C   128
#define NB1     98     // ceil(N_NUC / 1024) for the scan
#define NPART   8
#define R_PER_P (N_NUC_C / NPART)          // 12500 receivers per partition
#define SBLK    784                        // blocks per partition in scatter
#define STHREADS (SBLK * 256)              // 200704 threads per partition
#define LDS_USTR 17                        // uint row stride (16 packed + 1 pad)
#define RANK_BLOCKS 6250                   // ceil(N_NN / 256)
#define PROJ_BLOCKS 1564                   // ceil(N_NUC/256) * 4

typedef __attribute__((ext_vector_type(8))) short bf16x8;
typedef __attribute__((ext_vector_type(4))) float f32x4;

__device__ __forceinline__ float silu_f(float y) {
    return y / (1.0f + __expf(-y));
}

// round-to-nearest-even f32->bf16, packed pair (a -> low 16, b -> high 16)
__device__ __forceinline__ unsigned pack_bf16x2(float a, float b) {
    unsigned ua = __float_as_uint(a); ua += 0x7FFFu + ((ua >> 16) & 1u);
    unsigned ub = __float_as_uint(b); ub += 0x7FFFu + ((ub >> 16) & 1u);
    return (ua >> 16) | (ub & 0xFFFF0000u);
}

__device__ __forceinline__ unsigned short bf16_of(float a) {
    unsigned ua = __float_as_uint(a); ua += 0x7FFFu + ((ua >> 16) & 1u);
    return (unsigned short)(ua >> 16);
}

// ---------------------------------------------------------------------------
// proj body (shared by combined and standalone kernels)
// ---------------------------------------------------------------------------
__device__ __forceinline__ void proj_body(
    int n, int pr, int c0,
    const float* __restrict__ s_embed, const float* __restrict__ r_embed,
    const float* __restrict__ W_s, const float* __restrict__ b_s,
    const float* __restrict__ W_r, const float* __restrict__ b_r,
    float* __restrict__ proj)
{
    const float* __restrict__ src = pr ? r_embed : s_embed;
    const float* __restrict__ W   = pr ? W_r : W_s;
    const float* __restrict__ b   = pr ? b_r : b_s;
    float* __restrict__ dst = proj + (size_t)pr * N_NUC_C * MSG_C;

    float acc[16];
    #pragma unroll
    for (int i = 0; i < 16; ++i) acc[i] = b[c0 + i];

    const float* row = src + (size_t)n * EMB_C;
    #pragma unroll 4
    for (int k = 0; k < EMB_C; k += 4) {
        const float4 rv = *reinterpret_cast<const float4*>(row + k);
        #pragma unroll
        for (int i = 0; i < 16; ++i) {
            acc[i] = fmaf(rv.x, W[(k + 0) * MSG_C + c0 + i], acc[i]);
            acc[i] = fmaf(rv.y, W[(k + 1) * MSG_C + c0 + i], acc[i]);
            acc[i] = fmaf(rv.z, W[(k + 2) * MSG_C + c0 + i], acc[i]);
            acc[i] = fmaf(rv.w, W[(k + 3) * MSG_C + c0 + i], acc[i]);
        }
    }

    float4* d = reinterpret_cast<float4*>(dst + (size_t)n * MSG_C + c0);
    d[0] = make_float4(acc[0],  acc[1],  acc[2],  acc[3]);
    d[1] = make_float4(acc[4],  acc[5],  acc[6],  acc[7]);
    d[2] = make_float4(acc[8],  acc[9],  acc[10], acc[11]);
    d[3] = make_float4(acc[12], acc[13], acc[14], acc[15]);
}

// ---------------------------------------------------------------------------
// Combined kernel: first RANK_BLOCKS do the CSR rank pass (critical path,
// fabric-atomic latency-bound), remaining PROJ_BLOCKS do the projections
// (VALU/stream-bound). Independent work; co-residency overlaps the pipes.
// ---------------------------------------------------------------------------
__global__ __launch_bounds__(256) void proj_rank_kernel(
    const float* __restrict__ s_embed, const float* __restrict__ r_embed,
    const float* __restrict__ W_s, const float* __restrict__ b_s,
    const float* __restrict__ W_r, const float* __restrict__ b_r,
    float* __restrict__ proj,
    const int* __restrict__ receivers, int* __restrict__ cnt,
    int* __restrict__ rank)
{
    const int bid = blockIdx.x;
    if (bid < RANK_BLOCKS) {
        const int e = bid * 256 + threadIdx.x;
        if (e < N_NN_C) rank[e] = atomicAdd(&cnt[receivers[e]], 1);
        return;
    }
    const int pb  = bid - RANK_BLOCKS;       // 0..PROJ_BLOCKS-1
    const int sub = pb & 3;                  // {s,r} x {col half}
    const int n   = (pb >> 2) * 256 + threadIdx.x;
    if (n >= N_NUC_C) return;
    proj_body(n, sub >> 1, (sub & 1) * 16,
              s_embed, r_embed, W_s, b_s, W_r, b_r, proj);
}

// Standalone proj (fallback path)
__global__ __launch_bounds__(256) void proj_kernel(
    const float* __restrict__ s_embed, const float* __restrict__ r_embed,
    const float* __restrict__ W_s, const float* __restrict__ b_s,
    const float* __restrict__ W_r, const float* __restrict__ b_r,
    float* __restrict__ proj)
{
    const int n = blockIdx.x * blockDim.x + threadIdx.x;
    if (n >= N_NUC_C) return;
    const int sub = blockIdx.y;
    proj_body(n, sub >> 1, (sub & 1) * 16,
              s_embed, r_embed, W_s, b_s, W_r, b_r, proj);
}

// Exclusive scan of cnt[N_NUC] -> offsets. Three tiny kernels.
__global__ __launch_bounds__(256) void scan1_kernel(
    const int* __restrict__ cnt, int* __restrict__ excl, int* __restrict__ blockTot)
{
    __shared__ int waveTot[4];
    const int t = threadIdx.x, b = blockIdx.x;
    const int lane = t & 63, wid = t >> 6;
    const int base = b * 1024 + t * 4;

    int d0 = (base + 0 < N_NUC_C) ? cnt[base + 0] : 0;
    int d1 = (base + 1 < N_NUC_C) ? cnt[base + 1] : 0;
    int d2 = (base + 2 < N_NUC_C) ? cnt[base + 2] : 0;
    int d3 = (base + 3 < N_NUC_C) ? cnt[base + 3] : 0;
    const int s = d0 + d1 + d2 + d3;

    int incl = s;
    #pragma unroll
    for (int off = 1; off < 64; off <<= 1) {
        int v = __shfl_up(incl, off);
        if (lane >= off) incl += v;
    }
    const int wexcl = incl - s;
    if (lane == 63) waveTot[wid] = incl;
    __syncthreads();
    int wbase = 0;
    for (int w = 0; w < wid; ++w) wbase += waveTot[w];
    const int e0 = wbase + wexcl;

    if (base + 0 < N_NUC_C) excl[base + 0] = e0;
    if (base + 1 < N_NUC_C) excl[base + 1] = e0 + d0;
    if (base + 2 < N_NUC_C) excl[base + 2] = e0 + d0 + d1;
    if (base + 3 < N_NUC_C) excl[base + 3] = e0 + d0 + d1 + d2;
    if (t == 255) blockTot[b] = wbase + incl;
}

__global__ __launch_bounds__(128) void scan2_kernel(
    const int* __restrict__ blockTot, int* __restrict__ blockOff)
{
    __shared__ int sh[128];
    const int t = threadIdx.x;
    const int v = (t < NB1) ? blockTot[t] : 0;
    sh[t] = v;
    __syncthreads();
    #pragma unroll
    for (int off = 1; off < 128; off <<= 1) {
        int x = 0;
        if (t >= off) x = sh[t - off];
        __syncthreads();
        sh[t] += x;
        __syncthreads();
    }
    if (t < NB1) blockOff[t] = sh[t] - v;
}

__global__ __launch_bounds__(256) void scan3_kernel(
    const int* __restrict__ excl, const int* __restrict__ blockOff,
    int* __restrict__ offsets)
{
    const int n = blockIdx.x * blockDim.x + threadIdx.x;
    if (n < N_NUC_C) offsets[n] = excl[n] + blockOff[n >> 10];
    if (n == 0) offsets[N_NUC_C] = N_NN_C;
}

// ---------------------------------------------------------------------------
// Partition-local ATOMIC-FREE scatter (R7-proven).
// ---------------------------------------------------------------------------
__global__ __launch_bounds__(256) void scatter_pack8_kernel(
    const int* __restrict__ senders, const int* __restrict__ receivers,
    const int* __restrict__ rank, const int* __restrict__ offsets,
    int4* __restrict__ edge_pack)
{
    const int p    = blockIdx.x & 7;
    const int blk  = blockIdx.x >> 3;                 // 0..SBLK-1
    const int base = blk * 256 + threadIdx.x;         // 0..STHREADS-1
    const int rlo  = p * R_PER_P;
    const int rhi  = rlo + R_PER_P;

    #pragma unroll
    for (int k = 0; k < 8; ++k) {
        const int e = base + k * STHREADS;
        if (e < N_NN_C) {
            const int r = receivers[e];
            if (r >= rlo && r < rhi) {
                const int dst = offsets[r] + rank[e];
                edge_pack[dst] = make_int4(e, senders[e], r, 0);
            }
        }
    }
}

// ---------------------------------------------------------------------------
// Fused CSR edge compute + in-block segmented reduction, gate via MFMA
// (R12 structure + A-fragment bit-reinterpret instead of shift/mask).
// ---------------------------------------------------------------------------
__global__ __launch_bounds__(256) void fused_csr_kernel(
    const float* __restrict__ proj,      // [2][N_NUC][MSG]
    const float* __restrict__ e_embed,   // [N_NN][MSG]
    const int4*  __restrict__ edge_pack, // [N_NN] (e, s, r, 0) CSR order
    const int*   __restrict__ offsets,   // [N_NUC+1]
    const float* __restrict__ ln_scale,
    const float* __restrict__ ln_bias,
    const float* __restrict__ W_e,       // [MSG][MSG]
    float*       __restrict__ msg)       // [N_NUC][MSG], pre-zeroed
{
    __shared__ unsigned lds_ev[256 * LDS_USTR];  // bf16 ev rows -> reused for msg staging
    __shared__ unsigned lds_g [256 * LDS_USTR];  // bf16 gate rows
    __shared__ int      lds_r[256];

    const int t    = threadIdx.x;
    const int lane = t & 63;
    const int wb   = t & ~63;            // wave's first row (0,64,128,192)
    const int B0   = blockIdx.x * 256;   // first CSR slot of this block

    const int4 pk = edge_pack[B0 + t];
    const int e = pk.x, s = pk.y, r = pk.z;
    lds_r[t] = r;

    // ---- stage own ev row to LDS as bf16 ----
    {
        const float4* ee = reinterpret_cast<const float4*>(e_embed + (size_t)e * MSG_C);
        unsigned* evrow = &lds_ev[t * LDS_USTR];
        #pragma unroll
        for (int q = 0; q < 8; ++q) {
            const float4 v = ee[q];
            evrow[2*q+0] = pack_bf16x2(v.x, v.y);
            evrow[2*q+1] = pack_bf16x2(v.z, v.w);
        }
    }

    // ---- B fragments of W_e (bf16): lane holds k=8*(lane>>4)+i, n=lane&15 ----
    bf16x8 bf0, bf1;
    {
        const int kg = (lane >> 4) * 8;
        const int n0 = lane & 15;
        #pragma unroll
        for (int i = 0; i < 8; ++i) {
            bf0[i] = (short)bf16_of(W_e[(kg + i) * MSG_C + n0]);
            bf1[i] = (short)bf16_of(W_e[(kg + i) * MSG_C + 16 + n0]);
        }
    }

    __syncthreads();   // B1: all ev rows staged

    // ---- MFMA: gate = ev @ W_e, write bf16 gate rows to LDS ----
    {
        unsigned short* g16 = reinterpret_cast<unsigned short*>(lds_g);
        #pragma unroll
        for (int mt = 0; mt < 4; ++mt) {
            const int arow = wb + mt * 16 + (lane & 15);
            const unsigned* ar = &lds_ev[arow * LDS_USTR + ((lane >> 4) << 2)];
            union { unsigned u[4]; bf16x8 v; } cvt;
            cvt.u[0] = ar[0]; cvt.u[1] = ar[1]; cvt.u[2] = ar[2]; cvt.u[3] = ar[3];
            const bf16x8 af = cvt.v;    // bf16 row already in operand order
            f32x4 z = {0.f, 0.f, 0.f, 0.f};
            const f32x4 a0 = __builtin_amdgcn_mfma_f32_16x16x32_bf16(af, bf0, z, 0, 0, 0);
            const f32x4 a1 = __builtin_amdgcn_mfma_f32_16x16x32_bf16(af, bf1, z, 0, 0, 0);
            const int rbase = wb + mt * 16 + ((lane >> 4) << 2);
            #pragma unroll
            for (int rg = 0; rg < 4; ++rg) {
                g16[(rbase + rg) * (2 * LDS_USTR) + (lane & 15)]      = bf16_of(a0[rg]);
                g16[(rbase + rg) * (2 * LDS_USTR) + 16 + (lane & 15)] = bf16_of(a1[rg]);
            }
        }
    }

    __syncthreads();   // B2: all gate rows written

    // ---- own gate row -> registers ----
    float g[MSG_C];
    {
        const unsigned* gr = &lds_g[t * LDS_USTR];
        #pragma unroll
        for (int j = 0; j < 16; ++j) {
            const unsigned u = gr[j];
            g[2*j]   = __uint_as_float(u << 16);
            g[2*j+1] = __uint_as_float(u & 0xFFFF0000u);
        }
    }

    // ---- x = proj_s + proj_r, LayerNorm + SiLU, msg -> lds_ev (reuse) ----
    const float4* ps = reinterpret_cast<const float4*>(proj + (size_t)s * MSG_C);
    const float4* pq = reinterpret_cast<const float4*>(proj + (size_t)(N_NUC_C + r) * MSG_C);
    float x[MSG_C];
    #pragma unroll
    for (int q = 0; q < 8; ++q) {
        const float4 a = ps[q];
        const float4 b = pq[q];
        x[4*q+0] = a.x + b.x; x[4*q+1] = a.y + b.y;
        x[4*q+2] = a.z + b.z; x[4*q+3] = a.w + b.w;
    }

    float mu = 0.0f;
    #pragma unroll
    for (int c = 0; c < MSG_C; ++c) mu += x[c];
    mu *= (1.0f / MSG_C);
    float var = 0.0f;
    #pragma unroll
    for (int c = 0; c < MSG_C; ++c) { const float d = x[c] - mu; var = fmaf(d, d, var); }
    var *= (1.0f / MSG_C);
    const float rs = rsqrtf(var + 1e-6f);

    unsigned* orow = &lds_ev[t * LDS_USTR];
    #pragma unroll
    for (int i = 0; i < 16; ++i) {
        const int c0_ = 2*i, c1_ = 2*i + 1;
        const float y0 = (x[c0_] - mu) * rs * ln_scale[c0_] + ln_bias[c0_];
        const float y1 = (x[c1_] - mu) * rs * ln_scale[c1_] + ln_bias[c1_];
        orow[i] = pack_bf16x2(silu_f(y0) * g[c0_], silu_f(y1) * g[c1_]);
    }

    __syncthreads();   // B3: all msg rows staged

    // ---- segmented reduction over receivers in this block ----
    const int r0 = lds_r[0];
    const int r1 = lds_r[255];
    const int total = (r1 - r0 + 1) << 5;   // (#receivers) * 32 channels

    for (int p = t; p < total; p += 256) {
        const int n  = r0 + (p >> 5);
        const int ch = p & 31;
        int b  = offsets[n];
        int en = offsets[n + 1];
        const bool interior = (b >= B0) && (en <= B0 + 256);
        if (b < B0) b = B0;
        if (en > B0 + 256) en = B0 + 256;

        const int dw  = ch >> 1;
        const bool hi = (ch & 1);
        float sum = 0.0f;
        for (int q = b - B0; q < en - B0; ++q) {
            const unsigned u = lds_ev[q * LDS_USTR + dw];
            sum += __uint_as_float(hi ? (u & 0xFFFF0000u) : (u << 16));
        }

        float* dst = msg + (size_t)n * MSG_C + ch;
        if (interior)       *dst = sum;          // sole owner (incl. empty = 0)
        else if (en > b)    atomicAdd(dst, sum); // straddling segment part
    }
}

// ---------------------------------------------------------------------------
// Fallback (tiny ws): R1 atomic edge kernel
// ---------------------------------------------------------------------------
__global__ __launch_bounds__(256) void edge_kernel(
    const float* __restrict__ proj, const float* __restrict__ e_embed,
    const int* __restrict__ senders, const int* __restrict__ receivers,
    const float* __restrict__ ln_scale, const float* __restrict__ ln_bias,
    const float* __restrict__ W_e, float* __restrict__ msg)
{
    const int e = blockIdx.x * blockDim.x + threadIdx.x;
    if (e >= N_NN_C) return;
    const int s = senders[e];
    const int r = receivers[e];
    const float4* ps = reinterpret_cast<const float4*>(proj + (size_t)s * MSG_C);
    const float4* pq = reinterpret_cast<const float4*>(proj + (size_t)(N_NUC_C + r) * MSG_C);
    float x[MSG_C];
    #pragma unroll
    for (int q = 0; q < 8; ++q) {
        const float4 a = ps[q];
        const float4 b = pq[q];
        x[4*q+0] = a.x + b.x; x[4*q+1] = a.y + b.y;
        x[4*q+2] = a.z + b.z; x[4*q+3] = a.w + b.w;
    }
    float mu = 0.0f;
    #pragma unroll
    for (int c = 0; c < MSG_C; ++c) mu += x[c];
    mu *= (1.0f / MSG_C);
    float var = 0.0f;
    #pragma unroll
    for (int c = 0; c < MSG_C; ++c) { const float d = x[c] - mu; var = fmaf(d, d, var); }
    var *= (1.0f / MSG_C);
    const float rs = rsqrtf(var + 1e-6f);
    #pragma unroll
    for (int c = 0; c < MSG_C; ++c) {
        const float y = (x[c] - mu) * rs * ln_scale[c] + ln_bias[c];
        x[c] = silu_f(y);
    }
    float ev[MSG_C];
    const float4* ee = reinterpret_cast<const float4*>(e_embed + (size_t)e * MSG_C);
    #pragma unroll
    for (int q = 0; q < 8; ++q) {
        const float4 v = ee[q];
        ev[4*q+0] = v.x; ev[4*q+1] = v.y; ev[4*q+2] = v.z; ev[4*q+3] = v.w;
    }
    float g[MSG_C];
    #pragma unroll
    for (int c = 0; c < MSG_C; ++c) g[c] = 0.0f;
    #pragma unroll
    for (int k = 0; k < MSG_C; ++k) {
        const float ek = ev[k];
        #pragma unroll
        for (int c = 0; c < MSG_C; ++c) g[c] = fmaf(ek, W_e[k * MSG_C + c], g[c]);
    }
    float* mrow = msg + (size_t)r * MSG_C;
    #pragma unroll
    for (int c = 0; c < MSG_C; ++c) atomicAdd(mrow + c, x[c] * g[c]);
}

// ---------------------------------------------------------------------------
// Kernel C: out[n][j] = silu( (msg[n] . W_out[:,j]) * norm[n] )
// ---------------------------------------------------------------------------
__global__ __launch_bounds__(256) void out_kernel(
    const float* __restrict__ msg, const float* __restrict__ norm,
    const float* __restrict__ W_out, float* __restrict__ out)
{
    const int j     = threadIdx.x & (OUT_C - 1);
    const int local = threadIdx.x >> 7;

    float w[MSG_C];
    #pragma unroll
    for (int k = 0; k < MSG_C; ++k) w[k] = W_out[k * OUT_C + j];

    for (int n = blockIdx.x * 2 + local; n < N_NUC_C; n += gridDim.x * 2) {
        const float4* m4 = reinterpret_cast<const float4*>(msg + (size_t)n * MSG_C);
        float acc = 0.0f;
        #pragma unroll
        for (int q = 0; q < 8; ++q) {
            const float4 mv = m4[q];
            acc = fmaf(mv.x, w[4*q+0], acc);
            acc = fmaf(mv.y, w[4*q+1], acc);
            acc = fmaf(mv.z, w[4*q+2], acc);
            acc = fmaf(mv.w, w[4*q+3], acc);
        }
        acc *= norm[n];
        out[(size_t)n * OUT_C + j] = silu_f(acc);
    }
}

extern "C" void kernel_launch(void* const* d_in, const int* in_sizes, int n_in,
                              void* d_out, int out_size, void* d_ws, size_t ws_size,
                              hipStream_t stream) {
    const float* s_embed   = (const float*)d_in[0];
    const float* r_embed   = (const float*)d_in[1];
    const float* e_embed   = (const float*)d_in[2];
    const float* norm      = (const float*)d_in[3];
    const int*   senders   = (const int*)d_in[4];
    const int*   receivers = (const int*)d_in[5];
    const float* W_s       = (const float*)d_in[6];
    const float* b_s       = (const float*)d_in[7];
    const float* W_r       = (const float*)d_in[8];
    const float* b_r       = (const float*)d_in[9];
    const float* ln_scale  = (const float*)d_in[10];
    const float* ln_bias   = (const float*)d_in[11];
    const float* W_e       = (const float*)d_in[12];
    const float* W_out     = (const float*)d_in[13];
    float* out = (float*)d_out;

    char* ws = (char*)d_ws;
    size_t off = 0;
    auto alloc = [&](size_t bytes) { char* p = ws + off; off += (bytes + 255) & ~(size_t)255; return p; };

    float* proj      = (float*)alloc((size_t)2 * N_NUC_C * MSG_C * 4); // 25.6 MB
    float* msg       = (float*)alloc((size_t)N_NUC_C * MSG_C * 4);     // 12.8 MB
    const size_t off_min = off;                                        // 38.4 MB
    int*   cnt       = (int*)  alloc((size_t)N_NUC_C * 4);
    int*   excl      = (int*)  alloc((size_t)N_NUC_C * 4);
    int*   offsets   = (int*)  alloc((size_t)(N_NUC_C + 1) * 4);
    int*   blockTot  = (int*)  alloc(128 * 4);
    int*   blockOff  = (int*)  alloc(128 * 4);
    int*   rank      = (int*)  alloc((size_t)N_NN_C * 4);              // 6.4 MB
    int4*  edge_pack = (int4*) alloc((size_t)N_NN_C * 16);             // 25.6 MB
    const size_t off_full = off;                                       // ~72 MB

    if (off_full <= ws_size) {
        // --- [proj || rank] combined + scan + partition scatter +
        //     fused edge-compute/reduce with MFMA gate ---
        hipMemsetAsync(cnt, 0, (size_t)N_NUC_C * 4, stream);
        hipMemsetAsync(msg, 0, (size_t)N_NUC_C * MSG_C * 4, stream);
        proj_rank_kernel<<<RANK_BLOCKS + PROJ_BLOCKS, 256, 0, stream>>>(
            s_embed, r_embed, W_s, b_s, W_r, b_r, proj, receivers, cnt, rank);
        scan1_kernel<<<NB1, 256, 0, stream>>>(cnt, excl, blockTot);
        scan2_kernel<<<1, 128, 0, stream>>>(blockTot, blockOff);
        scan3_kernel<<<(N_NUC_C + 255) / 256, 256, 0, stream>>>(excl, blockOff, offsets);
        scatter_pack8_kernel<<<NPART * SBLK, 256, 0, stream>>>(
            senders, receivers, rank, offsets, edge_pack);
        fused_csr_kernel<<<N_NN_C / 256, 256, 0, stream>>>(
            proj, e_embed, edge_pack, offsets, ln_scale, ln_bias, W_e, msg);
    } else if (off_min <= ws_size) {
        // --- fallback: R1 atomic path ---
        dim3 pgrid((N_NUC_C + 255) / 256, 4);
        proj_kernel<<<pgrid, 256, 0, stream>>>(s_embed, r_embed, W_s, b_s, W_r, b_r, proj);
        hipMemsetAsync(msg, 0, (size_t)N_NUC_C * MSG_C * 4, stream);
        edge_kernel<<<(N_NN_C + 255) / 256, 256, 0, stream>>>(
            proj, e_embed, senders, receivers, ln_scale, ln_bias, W_e, msg);
    }

    out_kernel<<<2048, 256, 0, stream>>>(msg, norm, W_out, out);
}